// Round 9
// baseline (2157.539 us; speedup 1.0000x reference)
//
#include <hip/hip_runtime.h>
#include <hip/hip_bf16.h>
#include <math.h>

#define BB 256
#define TT 64
#define UU 512
#define XWD 33554432   // per-dir xw elements (64*256*2048)
#define WSTR 520       // LDS weight row stride (512 + 8 pad)

typedef __hip_bfloat16 bf16;
typedef __attribute__((ext_vector_type(8))) short sh8;     // 8 x bf16
typedef __attribute__((ext_vector_type(4))) short sh4;     // 4 x bf16
typedef __attribute__((ext_vector_type(4))) float floatx4; // MFMA acc
typedef __attribute__((ext_vector_type(4))) unsigned int ui4;

union U16 { ui4 u; sh8 s; };

__device__ __forceinline__ float bf2f(short s) {
    union { unsigned int u; float f; } v;
    v.u = ((unsigned int)(unsigned short)s) << 16;
    return v.f;
}
__device__ __forceinline__ short f2bf_bits(float f) {
    union { float f; unsigned u; } v; v.f = f;
    unsigned rr = v.u + 0x7fff + ((v.u >> 16) & 1);   // RNE, matches __float2bfloat16
    return (short)(rr >> 16);
}
__device__ __forceinline__ float fsig(float x)  { return 1.0f / (1.0f + __expf(-x)); }
__device__ __forceinline__ float ftanh(float x) { return 2.0f / (1.0f + __expf(-2.0f * x)) - 1.0f; }

// agent-coherent dword store (MALL-level, fence-free): fire-and-forget
__device__ __forceinline__ void coh_store_dw(unsigned* p, unsigned v) {
    asm volatile("global_store_dword %[ad], %[dv], off sc0 sc1"
                 :: [ad]"v"(p), [dv]"v"(v) : "memory");
}

// async global->LDS, 16B per lane. LDS dest must be wave-uniform base + lane*16.
#define GLDS(gp, lp) __builtin_amdgcn_global_load_lds( \
    (const __attribute__((address_space(1))) unsigned int*)(const void*)(gp), \
    (__attribute__((address_space(3))) unsigned int*)(void*)(lp), 16, 0, 0)

// ---------------- transpose + fp32->bf16 convert ----------------
__global__ void transpose_conv_kernel(const float* __restrict__ in, bf16* __restrict__ out,
                                      int K, int N, int out_stride) {
    __shared__ float tile[32][33];
    int k0 = blockIdx.y * 32;
    int n0 = blockIdx.x * 32;
    int tid = threadIdx.x;
    int nn = tid & 31, kk = tid >> 5;
    #pragma unroll
    for (int j = 0; j < 4; ++j)
        tile[kk + j * 8][nn] = in[(size_t)(k0 + kk + j * 8) * N + n0 + nn];
    __syncthreads();
    int kk2 = tid & 31, nn2 = tid >> 5;
    #pragma unroll
    for (int j = 0; j < 4; ++j)
        out[(size_t)(n0 + nn2 + j * 8) * out_stride + k0 + kk2] =
            __float2bfloat16(tile[kk2][nn2 + j * 8]);
}

// ---------------- mean-pool over 10x10 spatial ----------------
__global__ void pool_kernel(const float* __restrict__ enc, float* __restrict__ pooled) {
    int b = blockIdx.y;
    int e = blockIdx.x * 256 + threadIdx.x;
    const float* p = enc + (size_t)b * 100 * 2048 + e;
    float s = 0.f;
    #pragma unroll 4
    for (int i = 0; i < 100; ++i) s += p[(size_t)i * 2048];
    pooled[(size_t)b * 2048 + e] = s * 0.01f;
}

// ---------------- embedding gather -> bf16, [t][b][256] layout ----------------
__global__ void embed_kernel(const int* __restrict__ seq, const float* __restrict__ emb,
                             bf16* __restrict__ tok) {
    int i = blockIdx.x;            // b*T + t
    int e = threadIdx.x;
    int b = i >> 6, t = i & 63;
    tok[((size_t)t * BB + b) * 256 + e] = __float2bfloat16(emb[(size_t)seq[i] * 256 + e]);
}

// ---------------- LDS-staged GEMM: out = act(A @ Wt^T + b) ----------------
__global__ __launch_bounds__(256)
void gemm_tile(const bf16* __restrict__ A, const bf16* __restrict__ Wt,
               const float* __restrict__ bias, bf16* __restrict__ out,
               int M, int N, int K, int relu, int mode) {
    __shared__ __align__(16) bf16 As[128 * 32];
    __shared__ __align__(16) bf16 Bs[128 * 32];
    const int tid = threadIdx.x;
    const int w = tid >> 6, lane = tid & 63;
    const int lm = lane & 15, q = lane >> 4;
    const int m0 = blockIdx.y * 128;
    const int n0 = blockIdx.x * 128;
    const int wm = (w & 1) * 64, wn = (w >> 1) * 64;

    const int srow = tid >> 2;
    const int sk8  = (tid & 3) * 8;
    const bf16* ga0 = A  + (size_t)(m0 + srow) * K + sk8;
    const bf16* ga1 = A  + (size_t)(m0 + 64 + srow) * K + sk8;
    const bf16* gb0 = Wt + (size_t)(n0 + srow) * K + sk8;
    const bf16* gb1 = Wt + (size_t)(n0 + 64 + srow) * K + sk8;
    bf16* la0 = As + tid * 8;
    bf16* la1 = As + 2048 + tid * 8;
    bf16* lb0 = Bs + tid * 8;
    bf16* lb1 = Bs + 2048 + tid * 8;

    floatx4 acc[4][4];
    #pragma unroll
    for (int i = 0; i < 4; ++i)
        #pragma unroll
        for (int j = 0; j < 4; ++j) acc[i][j] = (floatx4){0.f, 0.f, 0.f, 0.f};

    const bf16* ra[4];
    const bf16* rb[4];
    #pragma unroll
    for (int i = 0; i < 4; ++i) ra[i] = As + (wm + i * 16 + lm) * 32 + q * 8;
    #pragma unroll
    for (int j = 0; j < 4; ++j) rb[j] = Bs + (wn + j * 16 + lm) * 32 + q * 8;

    for (int k0 = 0; k0 < K; k0 += 32) {
        GLDS(ga0 + k0, la0);
        GLDS(ga1 + k0, la1);
        GLDS(gb0 + k0, lb0);
        GLDS(gb1 + k0, lb1);
        __syncthreads();
        sh8 af[4], bfr[4];
        #pragma unroll
        for (int i = 0; i < 4; ++i) af[i] = *(const sh8*)ra[i];
        #pragma unroll
        for (int j = 0; j < 4; ++j) bfr[j] = *(const sh8*)rb[j];
        #pragma unroll
        for (int i = 0; i < 4; ++i)
            #pragma unroll
            for (int j = 0; j < 4; ++j)
                acc[i][j] = __builtin_amdgcn_mfma_f32_16x16x32_bf16(af[i], bfr[j], acc[i][j], 0, 0, 0);
        __syncthreads();
    }

    if (mode == 0) {
        #pragma unroll
        for (int i = 0; i < 4; ++i)
            #pragma unroll
            for (int j = 0; j < 4; ++j) {
                int n = n0 + wn + j * 16 + lm;
                float bv = bias[n];
                #pragma unroll
                for (int r = 0; r < 4; ++r) {
                    int m = m0 + wm + i * 16 + q * 4 + r;
                    float v = acc[i][j][r] + bv;
                    if (relu) v = fmaxf(v, 0.f);
                    out[(size_t)m * N + n] = __float2bfloat16(v);
                }
            }
    } else {
        #pragma unroll
        for (int i = 0; i < 4; ++i) {
            int mb = m0 + wm + i * 16 + q * 4;
            int t = mb >> 8;
            int bq = (mb >> 2) & 63;
            #pragma unroll
            for (int j = 0; j < 4; ++j) {
                int n = n0 + wn + j * 16 + lm;
                float bv = bias[n];
                size_t base = ((((size_t)(t * 64 + bq) * 32 + ((n >> 4) & 31)) * 16
                               + (n & 15)) * 16) + (n >> 9) * 4;
                sh4 sv;
                #pragma unroll
                for (int r = 0; r < 4; ++r)
                    sv[r] = f2bf_bits(acc[i][j][r] + bv);
                *(sh4*)(out + base) = sv;
            }
        }
    }
}

// ---------------- persistent LSTM: tagged self-validating h exchange ----------------
// grid (32 u-tiles, 4 b-groups, 2 dirs) = 256 blocks, 512 thr, ~118KB LDS -> 1 blk/CU.
// h stored as u32 (tag<<16)|bf16bits, sc0/sc1 (MALL-coherent). The data word IS the
// flag: producers fire-and-forget 4 dword stores; consumers poll-load their 64 words
// until all tags match. No fences, no flags, no end-of-step barrier. Mid-step
// __syncthreads only for the LDS part exchange (double-buffered for WAR safety).
// Tag correctness: producer writes h(s+2) only after reading ALL h(s+1), which
// requires every block's h(s) reads done -> no overwrite-before-read; tag T vs
// stale T-2 never aliases.
__global__ __launch_bounds__(512, 2)
void lstm_seq(const bf16* __restrict__ xw, const bf16* __restrict__ Wht,
              const int* __restrict__ seq, unsigned* __restrict__ h0b,
              unsigned* __restrict__ h1b, bf16* __restrict__ seqout, int tbase) {
    const int dir = blockIdx.z;
    const int u0 = blockIdx.x * 16;
    const int tid = threadIdx.x;
    const int w = tid >> 6, lane = tid & 63;
    const int lm = lane & 15, q = lane >> 4;
    const int kh = w >> 2;           // k-half
    const int wb = w & 3;            // b-group wave
    const int b0blk = blockIdx.y * 64;
    const int b0w = b0blk + wb * 16;

    __shared__ float part[2][4 * 64 * 17];       // 34816 B (double-buffered)
    __shared__ __align__(16) bf16 lW[64 * WSTR]; // 66560 B
    __shared__ int sq[TT * 64];                  // 16384 B  (~118KB total -> 1 blk/CU)

    const size_t hdb = (size_t)dir * BB * UU;    // u32 units
    const int koff = kh * 256;                   // 8 kc * 32
    const bf16* Wd = Wht + (size_t)dir * 2048 * UU;

    // one-time seq preload: sq[t*64 + bb] = seq[(b0blk+bb)*TT + t]
    for (int i = tid; i < TT * 64; i += 512) {
        int tt = i >> 6, bb = i & 63;
        sq[i] = seq[(b0blk + bb) * TT + tt];
    }
    // one-time weight preload: LDS[g*16+lmr][k] = Wd[(g*512 + u0 + lmr)*512 + k]
    {
        int row = tid >> 3;                  // 0..63
        int ck  = (tid & 7) * 64;
        int g = row >> 4, lmr = row & 15;
        const bf16* gsrc = Wd + (size_t)(g * UU + u0 + lmr) * UU + ck;
        bf16* ldst = lW + row * WSTR + ck;
        #pragma unroll
        for (int j = 0; j < 8; ++j)
            *(sh8*)(ldst + j * 8) = *(const sh8*)(gsrc + j * 8);
    }
    __syncthreads();

    const bf16* lwp0 = lW + (0 * 16 + lm) * WSTR + q * 8 + koff;
    const bf16* lwp1 = lW + (1 * 16 + lm) * WSTR + q * 8 + koff;
    const bf16* lwp2 = lW + (2 * 16 + lm) * WSTR + q * 8 + koff;
    const bf16* lwp3 = lW + (3 * 16 + lm) * WSTR + q * 8 + koff;

    // register state for this lane's (b = b0w + q*4 + r, u = u0 + lm) tile (kh=0 waves)
    float creg[4] = {0.f, 0.f, 0.f, 0.f};
    float hreg[4] = {0.f, 0.f, 0.f, 0.f};

    // xw prefetch for step 0 (kh=0 waves only)
    sh8 x0p = (sh8)0, x1p = (sh8)0;
    const size_t xwbase = (size_t)dir * XWD;
    if (kh == 0) {
        const int t0s = dir ? (TT - 1) : 0;
        const bf16* xwp = xw + xwbase
            + (((size_t)(t0s * 64 + (b0w >> 2) + q) * 32 + (u0 >> 4)) * 16 + lm) * 16;
        x0p = *(const sh8*)xwp;
        x1p = *(const sh8*)(xwp + 8);
    }

    for (int s = 0; s < TT; ++s) {
        const int t = dir ? (TT - 1 - s) : s;
        const unsigned* hin = (s & 1) ? h1b : h0b;
        unsigned*      hout = (s & 1) ? h0b : h1b;

        // --- poll-load tagged h: 64 u32/lane, 16 dwordx4 in one asm block ---
        const unsigned* hA = hin + hdb + (size_t)(b0w + lm) * UU + q * 8 + koff;
        const unsigned tgtw = (unsigned)(tbase + s) << 16;
        ui4 w0, w1, w2, w3, w4, w5, w6, w7, w8, w9, w10, w11, w12, w13, w14, w15;
        for (;;) {
            asm volatile(
                "global_load_dwordx4 %[a0], %[ad], off sc0 sc1\n\t"
                "global_load_dwordx4 %[a1], %[ad], off offset:16 sc0 sc1\n\t"
                "global_load_dwordx4 %[a2], %[ad], off offset:128 sc0 sc1\n\t"
                "global_load_dwordx4 %[a3], %[ad], off offset:144 sc0 sc1\n\t"
                "global_load_dwordx4 %[a4], %[ad], off offset:256 sc0 sc1\n\t"
                "global_load_dwordx4 %[a5], %[ad], off offset:272 sc0 sc1\n\t"
                "global_load_dwordx4 %[a6], %[ad], off offset:384 sc0 sc1\n\t"
                "global_load_dwordx4 %[a7], %[ad], off offset:400 sc0 sc1\n\t"
                "global_load_dwordx4 %[a8], %[ad], off offset:512 sc0 sc1\n\t"
                "global_load_dwordx4 %[a9], %[ad], off offset:528 sc0 sc1\n\t"
                "global_load_dwordx4 %[a10], %[ad], off offset:640 sc0 sc1\n\t"
                "global_load_dwordx4 %[a11], %[ad], off offset:656 sc0 sc1\n\t"
                "global_load_dwordx4 %[a12], %[ad], off offset:768 sc0 sc1\n\t"
                "global_load_dwordx4 %[a13], %[ad], off offset:784 sc0 sc1\n\t"
                "global_load_dwordx4 %[a14], %[ad], off offset:896 sc0 sc1\n\t"
                "global_load_dwordx4 %[a15], %[ad], off offset:912 sc0 sc1\n\t"
                "s_waitcnt vmcnt(0)"
                : [a0]"=&v"(w0), [a1]"=&v"(w1), [a2]"=&v"(w2), [a3]"=&v"(w3),
                  [a4]"=&v"(w4), [a5]"=&v"(w5), [a6]"=&v"(w6), [a7]"=&v"(w7),
                  [a8]"=&v"(w8), [a9]"=&v"(w9), [a10]"=&v"(w10), [a11]"=&v"(w11),
                  [a12]"=&v"(w12), [a13]"=&v"(w13), [a14]"=&v"(w14), [a15]"=&v"(w15)
                : [ad]"v"(hA)
                : "memory");
            if (s == 0) break;   // initial state: memset zeros, no tag check
            #define CHK8(A,B) ((A[0]^tgtw)|(A[1]^tgtw)|(A[2]^tgtw)|(A[3]^tgtw)| \
                               (B[0]^tgtw)|(B[1]^tgtw)|(B[2]^tgtw)|(B[3]^tgtw))
            unsigned accx = CHK8(w0, w1) | CHK8(w2, w3) | CHK8(w4, w5) | CHK8(w6, w7)
                          | CHK8(w8, w9) | CHK8(w10, w11) | CHK8(w12, w13) | CHK8(w14, w15);
            #undef CHK8
            if (__all((accx & 0xffff0000u) == 0u)) break;
            __builtin_amdgcn_s_sleep(1);
        }
        // repack low16s -> 8 x sh8 MFMA fragments
        sh8 hv[8];
        #define PK(D, A, B) { U16 _u; \
            _u.u = (ui4){ (A[0] & 0xffffu) | (A[1] << 16), (A[2] & 0xffffu) | (A[3] << 16), \
                          (B[0] & 0xffffu) | (B[1] << 16), (B[2] & 0xffffu) | (B[3] << 16) }; \
            D = _u.s; }
        PK(hv[0], w0, w1)  PK(hv[1], w2, w3)  PK(hv[2], w4, w5)  PK(hv[3], w6, w7)
        PK(hv[4], w8, w9)  PK(hv[5], w10, w11) PK(hv[6], w12, w13) PK(hv[7], w14, w15)
        #undef PK

        floatx4 acc0, acc1, acc2, acc3;
        if (kh == 0) {
            acc0 = (floatx4){bf2f(x0p[0]), bf2f(x0p[1]), bf2f(x0p[2]), bf2f(x0p[3])};
            acc1 = (floatx4){bf2f(x0p[4]), bf2f(x0p[5]), bf2f(x0p[6]), bf2f(x0p[7])};
            acc2 = (floatx4){bf2f(x1p[0]), bf2f(x1p[1]), bf2f(x1p[2]), bf2f(x1p[3])};
            acc3 = (floatx4){bf2f(x1p[4]), bf2f(x1p[5]), bf2f(x1p[6]), bf2f(x1p[7])};
        } else {
            acc0 = acc1 = acc2 = acc3 = (floatx4){0.f, 0.f, 0.f, 0.f};
        }

        #pragma unroll
        for (int kc = 0; kc < 8; ++kc) {
            sh8 a0 = *(const sh8*)(lwp0 + kc * 32);
            sh8 a1 = *(const sh8*)(lwp1 + kc * 32);
            sh8 a2 = *(const sh8*)(lwp2 + kc * 32);
            sh8 a3 = *(const sh8*)(lwp3 + kc * 32);
            acc0 = __builtin_amdgcn_mfma_f32_16x16x32_bf16(hv[kc], a0, acc0, 0, 0, 0);
            acc1 = __builtin_amdgcn_mfma_f32_16x16x32_bf16(hv[kc], a1, acc1, 0, 0, 0);
            acc2 = __builtin_amdgcn_mfma_f32_16x16x32_bf16(hv[kc], a2, acc2, 0, 0, 0);
            acc3 = __builtin_amdgcn_mfma_f32_16x16x32_bf16(hv[kc], a3, acc3, 0, 0, 0);
        }

        float* pbuf = part[s & 1];
        if (kh == 1) {
            float* pp = pbuf + (wb * 64 + lane) * 17;
            #pragma unroll
            for (int r = 0; r < 4; ++r) {
                pp[r] = acc0[r]; pp[4 + r] = acc1[r];
                pp[8 + r] = acc2[r]; pp[12 + r] = acc3[r];
            }
        }
        __syncthreads();
        if (kh == 0) {
            const float* pp = pbuf + (wb * 64 + lane) * 17;
            #pragma unroll
            for (int r = 0; r < 4; ++r) {
                acc0[r] += pp[r]; acc1[r] += pp[4 + r];
                acc2[r] += pp[8 + r]; acc3[r] += pp[12 + r];
            }
            const int uu = u0 + lm;
            const unsigned tagw = (unsigned)(tbase + s + 1) << 16;
            #pragma unroll
            for (int r = 0; r < 4; ++r) {
                int b = b0w + q * 4 + r;
                bool m = (sq[t * 64 + wb * 16 + q * 4 + r] != 0);
                float cp = creg[r];
                float cn = fsig(acc1[r]) * cp + fsig(acc0[r]) * ftanh(acc2[r]);
                float hn = fsig(acc3[r]) * ftanh(cn);
                float hv2 = m ? hn : hreg[r];
                creg[r] = m ? cn : cp;
                hreg[r] = hv2;
                short hb = f2bf_bits(hv2);
                coh_store_dw(&hout[hdb + (size_t)b * UU + uu],
                             tagw | (unsigned)(unsigned short)hb);   // fire-and-forget
                if (seqout)
                    __builtin_nontemporal_store(hb,
                        (short*)&seqout[((size_t)t * BB + b) * 1024 + dir * UU + uu]);
            }
            // xw prefetch for next step (hidden under next poll)
            if (s + 1 < TT) {
                const int tn = dir ? (TT - 2 - s) : (s + 1);
                const bf16* xwp = xw + xwbase
                    + (((size_t)(tn * 64 + (b0w >> 2) + q) * 32 + (u0 >> 4)) * 16 + lm) * 16;
                x0p = *(const sh8*)xwp;
                x1p = *(const sh8*)(xwp + 8);
            }
        }
    }
}

// ---------------- feats = [pooled | h2f | h2b] (bf16); h2 is tagged u32 ----------------
__global__ void concat_kernel(const float* __restrict__ pooled, const unsigned* __restrict__ h2,
                              bf16* __restrict__ feats) {
    int b = blockIdx.x;
    for (int j = threadIdx.x; j < 3072; j += 256) {
        short v;
        if (j < 2048) v = f2bf_bits(pooled[(size_t)b * 2048 + j]);
        else {
            int u = j - 2048;
            int dir = u >> 9;
            int uu = u & 511;
            v = (short)(h2[((size_t)dir * BB + b) * UU + uu] & 0xffffu);
        }
        ((short*)feats)[(size_t)b * 3072 + j] = v;
    }
}

// ---------------- out = sigmoid(x2 @ W3 + b3), K=512 ----------------
__global__ void final_kernel(const bf16* __restrict__ x2, const float* __restrict__ W3,
                             const float* __restrict__ b3, float* __restrict__ out) {
    int b = blockIdx.x;
    int tid = threadIdx.x;
    float v = __bfloat162float(x2[(size_t)b * 512 + tid]) * W3[tid]
            + __bfloat162float(x2[(size_t)b * 512 + 256 + tid]) * W3[256 + tid];
    for (int off = 32; off > 0; off >>= 1) v += __shfl_down(v, off, 64);
    __shared__ float wsum[4];
    if ((tid & 63) == 0) wsum[tid >> 6] = v;
    __syncthreads();
    if (tid == 0) {
        float sum = wsum[0] + wsum[1] + wsum[2] + wsum[3] + b3[0];
        out[b] = 1.0f / (1.0f + expf(-sum));
    }
}

extern "C" void kernel_launch(void* const* d_in, const int* in_sizes, int n_in,
                              void* d_out, int out_size, void* d_ws, size_t ws_size,
                              hipStream_t stream) {
    const float* enc    = (const float*)d_in[0];
    const int*   seq    = (const int*)  d_in[1];
    const float* emb    = (const float*)d_in[2];
    const float* l1f_Wi = (const float*)d_in[3];
    const float* l1f_Wh = (const float*)d_in[4];
    const float* l1f_b  = (const float*)d_in[5];
    const float* l1b_Wi = (const float*)d_in[6];
    const float* l1b_Wh = (const float*)d_in[7];
    const float* l1b_b  = (const float*)d_in[8];
    const float* l2f_Wi = (const float*)d_in[9];
    const float* l2f_Wh = (const float*)d_in[10];
    const float* l2f_b  = (const float*)d_in[11];
    const float* l2b_Wi = (const float*)d_in[12];
    const float* l2b_Wh = (const float*)d_in[13];
    const float* l2b_b  = (const float*)d_in[14];
    const float* W1     = (const float*)d_in[15];
    const float* b1     = (const float*)d_in[16];
    const float* W2     = (const float*)d_in[17];
    const float* b2     = (const float*)d_in[18];
    const float* W3     = (const float*)d_in[19];
    const float* b3     = (const float*)d_in[20];

    // ---- workspace layout ----
    char* p = (char*)d_ws;
    bf16* tok      = (bf16*)p;  p += (size_t)TT * BB * 256 * 2;        // [t][b][256]
    bf16* lstm1out = (bf16*)p;  p += (size_t)TT * BB * 1024 * 2;       // [t][b][1024]
    bf16* xw       = (bf16*)p;  p += (size_t)2 * XWD * 2;              // mode-2 perm
    bf16* Wh1t     = (bf16*)p;  p += (size_t)2 * 2048 * 512 * 2;
    bf16* Wh2t     = (bf16*)p;  p += (size_t)2 * 2048 * 512 * 2;
    bf16* Wi1t     = (bf16*)p;  p += (size_t)2 * 2048 * 256 * 2;
    bf16* Wi2t     = (bf16*)p;  p += (size_t)2 * 2048 * 1024 * 2;
    bf16* W1t      = (bf16*)p;  p += (size_t)1024 * 3072 * 2;
    bf16* W2t      = (bf16*)p;  p += (size_t)512 * 1024 * 2;
    float* pooled  = (float*)p; p += (size_t)BB * 2048 * 4;
    bf16* feats    = (bf16*)p;  p += (size_t)BB * 3072 * 2;
    bf16* x1       = (bf16*)p;  p += (size_t)BB * 1024 * 2;
    bf16* x2       = (bf16*)p;  p += (size_t)BB * 512 * 2;
    unsigned* hb0  = (unsigned*)p; p += (size_t)2 * BB * UU * 4;       // tagged u32 h
    unsigned* hb1  = (unsigned*)p; p += (size_t)2 * BB * UU * 4;

    transpose_conv_kernel<<<dim3(64, 16), 256, 0, stream>>>(l1f_Wh, Wh1t,                    512, 2048, 512);
    transpose_conv_kernel<<<dim3(64, 16), 256, 0, stream>>>(l1b_Wh, Wh1t + (size_t)2048*512, 512, 2048, 512);
    transpose_conv_kernel<<<dim3(64, 16), 256, 0, stream>>>(l2f_Wh, Wh2t,                    512, 2048, 512);
    transpose_conv_kernel<<<dim3(64, 16), 256, 0, stream>>>(l2b_Wh, Wh2t + (size_t)2048*512, 512, 2048, 512);
    transpose_conv_kernel<<<dim3(64, 8),  256, 0, stream>>>(l1f_Wi, Wi1t,                    256, 2048, 256);
    transpose_conv_kernel<<<dim3(64, 8),  256, 0, stream>>>(l1b_Wi, Wi1t + (size_t)2048*256, 256, 2048, 256);
    transpose_conv_kernel<<<dim3(64, 32), 256, 0, stream>>>(l2f_Wi, Wi2t,                     1024, 2048, 1024);
    transpose_conv_kernel<<<dim3(64, 32), 256, 0, stream>>>(l2b_Wi, Wi2t + (size_t)2048*1024, 1024, 2048, 1024);
    transpose_conv_kernel<<<dim3(32, 96), 256, 0, stream>>>(W1, W1t, 3072, 1024, 3072);
    transpose_conv_kernel<<<dim3(16, 32), 256, 0, stream>>>(W2, W2t, 1024, 512, 1024);

    pool_kernel<<<dim3(8, BB), 256, 0, stream>>>(enc, pooled);
    embed_kernel<<<dim3(BB * TT), 256, 0, stream>>>(seq, emb, tok);

    // ---- layer 1: xw = tok @ Wi1^T + b (mode-2 perm), then one persistent launch ----
    hipMemsetAsync(hb0, 0, (size_t)2 * BB * UU * 4, stream);
    gemm_tile<<<dim3(16, 128), 256, 0, stream>>>(tok, Wi1t,                    l1f_b, xw,       16384, 2048, 256, 0, 2);
    gemm_tile<<<dim3(16, 128), 256, 0, stream>>>(tok, Wi1t + (size_t)2048*256, l1b_b, xw + XWD, 16384, 2048, 256, 0, 2);
    lstm_seq<<<dim3(32, 4, 2), 512, 0, stream>>>(xw, Wh1t, seq, hb0, hb1, lstm1out, 0);

    // ---- layer 2 ----
    hipMemsetAsync(hb0, 0, (size_t)2 * BB * UU * 4, stream);
    gemm_tile<<<dim3(16, 128), 256, 0, stream>>>(lstm1out, Wi2t,                     l2f_b, xw,       16384, 2048, 1024, 0, 2);
    gemm_tile<<<dim3(16, 128), 256, 0, stream>>>(lstm1out, Wi2t + (size_t)2048*1024, l2b_b, xw + XWD, 16384, 2048, 1024, 0, 2);
    lstm_seq<<<dim3(32, 4, 2), 512, 0, stream>>>(xw, Wh2t, seq, hb0, hb1, nullptr, TT);
    // s=63 writes hout=hb0 -> final h2 (tagged) in hb0

    // ---- head ----
    concat_kernel<<<dim3(BB), 256, 0, stream>>>(pooled, hb0, feats);
    gemm_tile<<<dim3(8, 2), 256, 0, stream>>>(feats, W1t, b1, x1, BB, 1024, 3072, 1, 0);
    gemm_tile<<<dim3(4, 2), 256, 0, stream>>>(x1, W2t, b2, x2, BB, 512, 1024, 1, 0);
    final_kernel<<<dim3(BB), 256, 0, stream>>>(x2, W3, b3, (float*)d_out);
}